// Round 7
// baseline (169.481 us; speedup 1.0000x reference)
//
#include <hip/hip_runtime.h>
#include <math.h>
#include <stdint.h>

#define NIMG   8
#define NA     30000      // H*W*A = 100*100*3
#define NQ4    7500       // NA/4 float4s
#define PRE_N  2000
#define POST_N 1000
#define NMS_TH 0.7f
#define DCLIP  4.135166556742356f   // log(1000/16)
#define IMGF   1600.0f
#define IMGM1  1599.0f
#define CAND_MAX 4096
#define HPITCH 4104       // 4096 + 8: replica bank-spread padding
#define BIG_BIN 64        // bins larger than this use the 2nd-level sub-radix
#define PREF_BIN 3064u    // keyof(1.0f)>>20: pass-1 prefilter pivot (fallback-safe)

// ws layout (floats): boxes [8][2000][4] @0, scores [8][2000] @64000,
//   valid(int) [8][2000] @80000, mask(u64) [8][2000][32] @96000.

// ---------------------------------------------------------------------------
// decode + store helper (verified math, unchanged)
// ---------------------------------------------------------------------------
__device__ __forceinline__ void decode_store(
    uint64_t key, unsigned int rank, int n, const float* __restrict__ breg,
    float* __restrict__ wsBoxes, float* __restrict__ wsScores,
    int* __restrict__ wsValid)
{
    unsigned int idx = (unsigned int)key;
    unsigned int k   = ~((unsigned int)(key >> 32));
    unsigned int u   = (k & 0x80000000u) ? (k & 0x7fffffffu) : ~k;
    float logit = __uint_as_float(u);
    float score = 1.0f / (1.0f + expf(-logit));

    int a = idx % 3, t = idx / 3, w = t % 100, h = t / 100;
    const float* bp = breg + n*120000 + (a*4)*10000 + t;
    float dx = bp[0], dy = bp[10000], dw = bp[20000], dh = bp[30000];

    float half = (a == 0) ? 32.0f : ((a == 1) ? 64.0f : 128.0f);
    float cx = w * 16.0f + 8.0f, cy = h * 16.0f + 8.0f;
    float x1 = cx - half, y1 = cy - half, x2 = cx + half, y2 = cy + half;
    float wd = x2 - x1 + 1.0f, hg = y2 - y1 + 1.0f;
    float cxr = x1 + 0.5f * wd, cyr = y1 + 0.5f * hg;
    dw = fminf(dw, DCLIP); dh = fminf(dh, DCLIP);
    float pcx = dx * wd + cxr, pcy = dy * hg + cyr;
    float pw = expf(dw) * wd, ph = expf(dh) * hg;
    float px1 = pcx - 0.5f * pw, py1 = pcy - 0.5f * ph;
    float px2 = pcx + 0.5f * pw - 1.0f, py2 = pcy + 0.5f * ph - 1.0f;
    px1 = fminf(fmaxf(px1, 0.0f), IMGM1);
    px2 = fminf(fmaxf(px2, 0.0f), IMGM1);
    py1 = fminf(fmaxf(py1, 0.0f), IMGM1);
    py2 = fminf(fmaxf(py2, 0.0f), IMGM1);
    float wss = px2 - px1 + 1.0f, hss = py2 - py1 + 1.0f;
    float xc = px1 + wss * 0.5f, yc = py1 + hss * 0.5f;
    int valid = (wss >= 0.0f) && (hss >= 0.0f) && (xc < IMGF) && (yc < IMGF);

    ((float4*)wsBoxes)[n * PRE_N + (int)rank] = make_float4(px1, py1, px2, py2);
    wsScores[n * PRE_N + (int)rank] = score;
    wsValid [n * PRE_N + (int)rank] = valid;
}

__device__ __forceinline__ unsigned int keyof(float f) {
    unsigned int u = __float_as_uint(f);
    return (u & 0x80000000u) ? ~u : (u | 0x80000000u);
}

// ---------------------------------------------------------------------------
// Kernel AB (verified R6): fused hist + suffix-sum + bin-grouped rank + decode
// with pass-1 prefilter and combined 2nd-level sub-radix for big bins.
// ---------------------------------------------------------------------------
__global__ __launch_bounds__(1024) void topk_decode(
    const float* __restrict__ obj, const float* __restrict__ breg,
    float* __restrict__ wsBoxes, float* __restrict__ wsScores,
    int* __restrict__ wsValid)
{
    const int n    = blockIdx.x;
    const int tid  = threadIdx.x;
    const int lane = tid & 63;
    const int wid  = tid >> 6;
    const int rep  = wid & 3;

    __shared__ unsigned int   histf[4 * HPITCH]; // counts -> bump bases (~64KB)
    __shared__ unsigned short sufx[4096];        // bin start slots
    __shared__ uint64_t       grp[CAND_MAX];     // bin-grouped keys (32KB)
    __shared__ uint64_t       grp2[CAND_MAX];    // sub-grouped big-bin keys (32KB)
    __shared__ unsigned int   wsum[16];
    __shared__ unsigned int   sbstar;
    __shared__ unsigned int   lbbase[16];        // grp2 region base per big bin
    __shared__ unsigned int   lbcnt, lbtot;

    // overlays on dead histogram replicas (valid only AFTER pass 2):
    unsigned int*   hist2  = histf;                                  // [16*256] u32
    unsigned short* sufx2  = (unsigned short*)(histf + HPITCH);      // [4096] u16
    unsigned char*  bin2lb = (unsigned char*)(histf + 2 * HPITCH);   // [4096] u8

    for (int b = tid; b < 4 * HPITCH; b += 1024) histf[b] = 0u;
    __syncthreads();

    // ---- load this thread's 8 float4s once (8 outstanding loads) -----------
    const float4* obj4 = (const float4*)(obj + n * NA);   // 7500 float4
    float4 v[8];
    #pragma unroll
    for (int kk = 0; kk < 7; ++kk) v[kk] = obj4[tid + kk * 1024];
    v[7] = make_float4(0.f, 0.f, 0.f, 0.f);
    if (tid < NQ4 - 7 * 1024) v[7] = obj4[tid + 7 * 1024];   // 332 tail threads

    // ---- pass 1: prefiltered replica histogram from registers --------------
    #pragma unroll
    for (int kk = 0; kk < 8; ++kk) {
        if (kk == 7 && tid >= NQ4 - 7 * 1024) continue;
        const float fv[4] = {v[kk].x, v[kk].y, v[kk].z, v[kk].w};
        #pragma unroll
        for (int e = 0; e < 4; ++e) {
            unsigned int b = keyof(fv[e]) >> 20;
            if (b >= PREF_BIN)
                atomicAdd(&histf[rep * HPITCH + b], 1u);
        }
    }
    __syncthreads();

    // ---- totals + fallback check -------------------------------------------
    unsigned int c0, c1, c2, c3;
    {
        const int b0 = tid * 4;
        c0 = histf[b0+0] + histf[HPITCH+b0+0] + histf[2*HPITCH+b0+0] + histf[3*HPITCH+b0+0];
        c1 = histf[b0+1] + histf[HPITCH+b0+1] + histf[2*HPITCH+b0+1] + histf[3*HPITCH+b0+1];
        c2 = histf[b0+2] + histf[HPITCH+b0+2] + histf[2*HPITCH+b0+2] + histf[3*HPITCH+b0+2];
        c3 = histf[b0+3] + histf[HPITCH+b0+3] + histf[2*HPITCH+b0+3] + histf[3*HPITCH+b0+3];
    }
    unsigned int p = c0 + c1 + c2 + c3;
    unsigned int s = p;
    #pragma unroll
    for (int off = 1; off < 64; off <<= 1) {
        unsigned int vv = __shfl_down(s, off);
        if (lane + off < 64) s += vv;
    }
    if (lane == 0) wsum[wid] = s;
    __syncthreads();
    unsigned int ftotal = 0;
    for (int w = 0; w < 16; ++w) ftotal += wsum[w];

    if (ftotal < PRE_N) {
        // fallback (block-uniform): top-up with the skipped low bins, redo reduce
        #pragma unroll
        for (int kk = 0; kk < 8; ++kk) {
            if (kk == 7 && tid >= NQ4 - 7 * 1024) continue;
            const float fv[4] = {v[kk].x, v[kk].y, v[kk].z, v[kk].w};
            #pragma unroll
            for (int e = 0; e < 4; ++e) {
                unsigned int b = keyof(fv[e]) >> 20;
                if (b < PREF_BIN)
                    atomicAdd(&histf[rep * HPITCH + b], 1u);
            }
        }
        __syncthreads();
        {
            const int b0 = tid * 4;
            c0 = histf[b0+0] + histf[HPITCH+b0+0] + histf[2*HPITCH+b0+0] + histf[3*HPITCH+b0+0];
            c1 = histf[b0+1] + histf[HPITCH+b0+1] + histf[2*HPITCH+b0+1] + histf[3*HPITCH+b0+1];
            c2 = histf[b0+2] + histf[HPITCH+b0+2] + histf[2*HPITCH+b0+2] + histf[3*HPITCH+b0+2];
            c3 = histf[b0+3] + histf[HPITCH+b0+3] + histf[2*HPITCH+b0+3] + histf[3*HPITCH+b0+3];
        }
        p = c0 + c1 + c2 + c3;
        s = p;
        #pragma unroll
        for (int off = 1; off < 64; off <<= 1) {
            unsigned int vv = __shfl_down(s, off);
            if (lane + off < 64) s += vv;
        }
        __syncthreads();            // wsum reuse
        if (lane == 0) wsum[wid] = s;
        __syncthreads();
    }

    // ---- suffix-scan (verified structure), bump-base conversion ------------
    unsigned int wafter = 0;
    for (int w = wid + 1; w < 16; ++w) wafter += wsum[w];
    unsigned int after = (s - p) + wafter;   // elems in bins > 4t+3
    {
        unsigned int S3 = after + c3;        // elems in bins > 4t+2
        unsigned int S2 = S3 + c2;           // elems in bins > 4t+1
        unsigned int S1 = S2 + c1;           // elems in bins > 4t+0
        unsigned int S0 = S1 + c0;
        if (S3 >= PRE_N && after < PRE_N) { sbstar = tid*4+3; }
        if (S2 >= PRE_N && S3    < PRE_N) { sbstar = tid*4+2; }
        if (S1 >= PRE_N && S2    < PRE_N) { sbstar = tid*4+1; }
        if (S0 >= PRE_N && S1    < PRE_N) { sbstar = tid*4+0; }
        sufx[tid*4+0] = (unsigned short)S1;
        sufx[tid*4+1] = (unsigned short)S2;
        sufx[tid*4+2] = (unsigned short)S3;
        sufx[tid*4+3] = (unsigned short)after;

        // counts -> per-replica bump bases (each thread touches only own bins)
        const unsigned int st[4] = {S1, S2, S3, after};
        #pragma unroll
        for (int q = 0; q < 4; ++q) {
            const int b = tid*4 + q;
            unsigned int base = st[q];
            #pragma unroll
            for (int r = 0; r < 4; ++r) {
                unsigned int c = histf[r * HPITCH + b];
                histf[r * HPITCH + b] = base;
                base += c;
            }
        }
    }
    __syncthreads();
    const unsigned int bstar = sbstar;

    // ---- pass 2: bin-grouped placement from registers ----------------------
    #pragma unroll
    for (int kk = 0; kk < 8; ++kk) {
        if (kk == 7 && tid >= NQ4 - 7 * 1024) continue;
        const float fv[4] = {v[kk].x, v[kk].y, v[kk].z, v[kk].w};
        #pragma unroll
        for (int e = 0; e < 4; ++e) {
            unsigned int k = keyof(fv[e]);
            unsigned int b = k >> 20;
            if (b < bstar) continue;
            int j = (tid + kk * 1024) * 4 + e;
            int a = j / 10000, t = j - a * 10000;
            uint64_t key = (((uint64_t)(~k)) << 32) | (unsigned int)(t * 3 + a);
            unsigned int slot = atomicAdd(&histf[rep * HPITCH + b], 1u);
            if (slot < CAND_MAX) grp[slot] = key;
        }
    }
    __syncthreads();

    // after pass2, histf[3][b] = end of bin b's slot region (replica 3 stays live)
    const unsigned int total = min(histf[3 * HPITCH + bstar], (unsigned int)CAND_MAX);

    // ---- init overlays (replicas 0..2 now dead) ----------------------------
    ((unsigned int*)bin2lb)[tid] = 0xFFFFFFFFu;              // 4096 B
    hist2[tid] = 0u; hist2[tid+1024] = 0u; hist2[tid+2048] = 0u; hist2[tid+3072] = 0u;
    if (tid == 0) { lbcnt = 0u; lbtot = 0u; }
    __syncthreads();

    // ---- detect big bins (each thread owns bins 4t..4t+3) ------------------
    #pragma unroll
    for (int q = 0; q < 4; ++q) {
        const unsigned int b = (unsigned int)(tid*4 + q);
        if (b >= bstar) {
            const unsigned int ge  = min(histf[3*HPITCH + b], (unsigned int)CAND_MAX);
            const unsigned int cnt = ge - (unsigned int)sufx[b];
            if (cnt > (unsigned int)BIG_BIN) {
                unsigned int pos = atomicAdd(&lbcnt, 1u);
                if (pos < 16u) {
                    bin2lb[b] = (unsigned char)pos;
                    lbbase[pos] = atomicAdd(&lbtot, cnt);
                }
            }
        }
    }
    __syncthreads();

    // ---- count pass: sub-histogram on key bits 19:12 of hi(=~k) ------------
    for (unsigned int slot = tid; slot < total; slot += 1024) {
        const unsigned int hi = (unsigned int)(grp[slot] >> 32);
        const unsigned int b  = 4095u - (hi >> 20);
        const unsigned char lb = bin2lb[b];
        if (lb != 0xFFu)
            atomicAdd(&hist2[(unsigned int)lb * 256u + ((hi >> 12) & 0xFFu)], 1u);
    }
    __syncthreads();

    // ---- per-big-bin 256-entry exclusive prefix: wave w <-> big bin w ------
    {
        const unsigned int nlb = min(lbcnt, 16u);
        if ((unsigned int)wid < nlb) {
            const int xb = wid * 256 + lane * 4;
            unsigned int e0 = hist2[xb+0], e1 = hist2[xb+1],
                         e2 = hist2[xb+2], e3 = hist2[xb+3];
            unsigned int tsum = e0 + e1 + e2 + e3;
            unsigned int inc = tsum;
            #pragma unroll
            for (int off = 1; off < 64; off <<= 1) {
                unsigned int vv = __shfl_up(inc, off);
                if (lane >= off) inc += vv;
            }
            unsigned int base = lbbase[wid] + (inc - tsum);
            hist2[xb+0] = base;             sufx2[xb+0] = (unsigned short)base;
            base += e0; hist2[xb+1] = base; sufx2[xb+1] = (unsigned short)base;
            base += e1; hist2[xb+2] = base; sufx2[xb+2] = (unsigned short)base;
            base += e2; hist2[xb+3] = base; sufx2[xb+3] = (unsigned short)base;
        }
    }
    __syncthreads();

    // ---- regroup big-bin elems into grp2 (bump on hist2) -------------------
    for (unsigned int slot = tid; slot < total; slot += 1024) {
        const uint64_t key = grp[slot];
        const unsigned int hi = (unsigned int)(key >> 32);
        const unsigned int b  = 4095u - (hi >> 20);
        const unsigned char lb = bin2lb[b];
        if (lb != 0xFFu) {
            unsigned int d = atomicAdd(&hist2[(unsigned int)lb * 256u + ((hi >> 12) & 0xFFu)], 1u);
            grp2[d] = key;
        }
    }
    __syncthreads();

    // ---- final: rank + decode ----------------------------------------------
    for (unsigned int slot = tid; slot < total; slot += 1024) {
        const uint64_t key = grp[slot];
        const unsigned int hi = (unsigned int)(key >> 32);   // = ~k
        const unsigned int b  = 4095u - (hi >> 20);
        const unsigned int gbeg = sufx[b];
        const unsigned int gend = min(histf[3 * HPITCH + b], (unsigned int)CAND_MAX);
        const unsigned char lb  = bin2lb[b];
        unsigned int rank;

        if (lb != 0xFFu) {
            // big bin: sub-group scan (avg ~5 elems), predicated 8-wide
            const unsigned int x   = (unsigned int)lb * 256u + ((hi >> 12) & 0xFFu);
            const unsigned int s2  = sufx2[x];
            const unsigned int e2v = hist2[x];     // post-bump = sub-group end
            rank = gbeg + (s2 - lbbase[lb]);
            for (unsigned int g = s2; g < e2v; g += 8u) {
                #pragma unroll
                for (int i = 0; i < 8; ++i) {
                    const unsigned int gi = g + (unsigned int)i;
                    const uint64_t vv = grp2[min(gi, e2v - 1u)];
                    rank += (gi < e2v && vv < key) ? 1u : 0u;
                }
            }
        } else {
            // small bin: 8-wide unrolled scan over grp
            rank = gbeg;
            unsigned int g = gbeg;
            for (; g + 8u <= gend; g += 8u) {
                uint64_t v0 = grp[g+0], v1 = grp[g+1], v2 = grp[g+2], v3 = grp[g+3];
                uint64_t v4 = grp[g+4], v5 = grp[g+5], v6 = grp[g+6], v7 = grp[g+7];
                unsigned int r0 = (v0 < key) ? 1u : 0u;
                r0 += (v1 < key) ? 1u : 0u;
                r0 += (v2 < key) ? 1u : 0u;
                r0 += (v3 < key) ? 1u : 0u;
                r0 += (v4 < key) ? 1u : 0u;
                r0 += (v5 < key) ? 1u : 0u;
                r0 += (v6 < key) ? 1u : 0u;
                r0 += (v7 < key) ? 1u : 0u;
                rank += r0;
            }
            for (; g < gend; ++g)
                rank += (grp[g] < key) ? 1u : 0u;
        }
        if (rank >= PRE_N) continue;
        decode_store(key, rank, n, breg, wsBoxes, wsScores, wsValid);
    }
}

// ---------------------------------------------------------------------------
// Kernel C (verified R11, unchanged): div-free IoU predicate, ballot mask
// word, LDS-staged contiguous store. One block (8 waves) per row-tile.
// ---------------------------------------------------------------------------
__global__ __launch_bounds__(512) void nms_mask(
    const float* __restrict__ wsBoxes, uint64_t* __restrict__ mask)
{
    const int blk  = blockIdx.x;
    const int n    = blk >> 5;
    const int i_t  = blk & 31;
    const int tid  = threadIdx.x;
    const int lane = tid & 63;
    const int wv   = tid >> 6;   // 0..7

    __shared__ uint64_t tile[64 * 33];   // padded pitch 33

    for (int idx = tid; idx < 64 * 33; idx += 512) tile[idx] = 0ull;
    __syncthreads();

    const int r = i_t * 64 + lane;
    float4 rb = (r < PRE_N) ? ((const float4*)wsBoxes)[n * PRE_N + r]
                            : make_float4(0.f, 0.f, 0.f, 0.f);
    float ra = (rb.z - rb.x + 1.0f) * (rb.w - rb.y + 1.0f);

    for (int j_t = i_t + wv; j_t < 32; j_t += 8) {
        const int j = j_t * 64 + lane;
        float4 cb = (j < PRE_N) ? ((const float4*)wsBoxes)[n * PRE_N + j]
                                : make_float4(3e30f, 3e30f, 3e30f, 3e30f);
        float ca = (cb.z - cb.x + 1.0f) * (cb.w - cb.y + 1.0f);
        const uint64_t jmask = (j_t == 31) ? 0xFFFFull : ~0ull;
        const bool diag = (j_t == i_t);
        uint64_t myword = 0ull;

        #pragma unroll
        for (int c = 0; c < 64; ++c) {
            float rx1 = __int_as_float(__builtin_amdgcn_readlane(__float_as_int(rb.x), c));
            float ry1 = __int_as_float(__builtin_amdgcn_readlane(__float_as_int(rb.y), c));
            float rx2 = __int_as_float(__builtin_amdgcn_readlane(__float_as_int(rb.z), c));
            float ry2 = __int_as_float(__builtin_amdgcn_readlane(__float_as_int(rb.w), c));
            float rar = __int_as_float(__builtin_amdgcn_readlane(__float_as_int(ra), c));
            float xx1 = fmaxf(rx1, cb.x), yy1 = fmaxf(ry1, cb.y);
            float xx2 = fminf(rx2, cb.z), yy2 = fminf(ry2, cb.w);
            float ww = fmaxf(xx2 - xx1 + 1.0f, 0.0f);
            float hh = fmaxf(yy2 - yy1 + 1.0f, 0.0f);
            float inter = ww * hh;
            float denom = rar + ca - inter;
            unsigned long long bits = __ballot(inter > NMS_TH * denom) & jmask;
            if (diag) bits &= (c == 63) ? 0ull : ((~0ull) << (c + 1));
            if (lane == c) myword = bits;
        }
        tile[lane * 33 + j_t] = myword;
    }
    __syncthreads();

    uint64_t* mrow = mask + ((size_t)n * PRE_N + (size_t)i_t * 64) * 32;
    const int cmax = (i_t == 31) ? 16 : 64;
    for (int idx = tid; idx < cmax * 32; idx += 512) {
        const int rr = idx >> 5, w = idx & 31;
        mrow[idx] = tile[rr * 33 + w];
    }
}

// ---------------------------------------------------------------------------
// Kernel D (rewritten R7): block-serial greedy NMS with parallel broadcast.
// 32 groups of 64 rows. Wave 0 does a 64-step intra-group serial scan using
// one preloaded u64 column word per row (branchless SALU chain); all 8 waves
// then OR the group's kept rows' future mask words into the LDS suppression
// vector. Early exit at kept>=1000 (unprocessed rows have rank>=1000 and are
// never stored -- same argument as the old asm early-exit). Replaces the
// single-wave 2000-row serial asm ring (~60cy/row, 50us measured).
// ---------------------------------------------------------------------------
__global__ __launch_bounds__(512) void nms_scan_select(
    const float* __restrict__ wsBoxes, const float* __restrict__ wsScores,
    const int* __restrict__ wsValid, const uint64_t* __restrict__ mask,
    float* __restrict__ out)
{
    const int n    = blockIdx.x;
    const int tid  = threadIdx.x;
    const int lane = tid & 63;
    const int wid  = tid >> 6;

    __shared__ unsigned int sup[64];   // 2048-bit suppression (1 = dead/invalid)
    __shared__ unsigned int kml, kmh;  // current group's kept mask
    __shared__ int skept, sdone;
    __shared__ int sscan[256];

    if (tid < 64) sup[tid] = 0u;
    if (tid == 0) { skept = 0; sdone = 0; }
    __syncthreads();

    // invalid bits -> sup (rows 2000..2047 forced invalid)
    if (tid < 500) {
        int4 vv = ((const int4*)(wsValid + n * PRE_N))[tid];
        unsigned int nib = (vv.x ? 0u : 1u) | ((vv.y ? 0u : 1u) << 1)
                         | ((vv.z ? 0u : 1u) << 2) | ((vv.w ? 0u : 1u) << 3);
        if (nib) atomicOr(&sup[tid >> 3], nib << ((tid & 7) * 4));
    } else {
        atomicOr(&sup[tid >> 3], 0xFu << ((tid & 7) * 4));
    }
    __syncthreads();

    const uint64_t* mrow = mask + (size_t)n * PRE_N * 32;

    // wave 0: preload group 0's intra column word (lane = row-in-group)
    unsigned int cl = 0u, ch = 0u;
    if (wid == 0) {
        uint64_t cw = (lane < PRE_N) ? mrow[(size_t)lane * 32 + 0] : 0ull;
        cl = (unsigned int)cw; ch = (unsigned int)(cw >> 32);
    }

    for (int g = 0; g < 32; ++g) {
        __syncthreads();            // sup from broadcast(g-1) ready; sdone visible
        if (sdone) break;

        if (wid == 0) {
            // prefetch next group's column word (latency hides under serial)
            unsigned int nl = 0u, nh = 0u;
            if (g < 31) {
                const int r = (g + 1) * 64 + lane;
                uint64_t cw = (r < PRE_N) ? mrow[(size_t)r * 32 + (g + 1)] : 0ull;
                nl = (unsigned int)cw; nh = (unsigned int)(cw >> 32);
            }

            unsigned long long win =
                ((unsigned long long)sup[2*g + 1] << 32) | sup[2*g];
            #pragma unroll
            for (int b = 0; b < 64; ++b) {
                unsigned long long t =
                    ((unsigned long long)(unsigned int)__builtin_amdgcn_readlane((int)ch, b) << 32)
                    | (unsigned int)__builtin_amdgcn_readlane((int)cl, b);
                // branchless: alive (bit==0) -> OR in its suppression word
                unsigned long long dead = (win >> b) & 1ull;
                win |= t & (dead - 1ull);     // dead=0 -> mask=~0; dead=1 -> 0
            }
            unsigned long long km = ~win;
            if (lane == 0) {
                sup[2*g]     = (unsigned int)win;
                sup[2*g + 1] = (unsigned int)(win >> 32);
                kml = (unsigned int)km;
                kmh = (unsigned int)(km >> 32);
                int nk = skept + __popcll(km);
                skept = nk;
                if (nk >= POST_N) sdone = 1;
            }
            cl = nl; ch = nh;
        }
        __syncthreads();            // km + sup writeback visible

        if (!sdone) {
            // broadcast: OR kept rows' mask words w>g into sup
            const int w = tid & 31;                 // u64 word index
            if (w > g) {
                const unsigned long long km =
                    ((unsigned long long)kmh << 32) | kml;
                const int r0 = (tid >> 5) * 4;      // 16 groups of 4 rows
                unsigned long long acc = 0ull;
                #pragma unroll
                for (int q = 0; q < 4; ++q) {
                    const int rl = r0 + q;
                    if ((km >> rl) & 1ull)
                        acc |= mrow[(size_t)(g * 64 + rl) * 32 + w];
                }
                if (acc) {
                    atomicOr(&sup[2*w],     (unsigned int)acc);
                    atomicOr(&sup[2*w + 1], (unsigned int)(acc >> 32));
                }
            }
        }
    }
    __syncthreads();

    // ---- compaction + output (keep = ~sup) ---------------------------------
    int c[8];
    int lsum = 0;
    const int base8 = tid * 8;
    if (tid < 256) {
        for (int q = 0; q < 8; ++q) {
            const int i = base8 + q;
            c[q] = (i < PRE_N) ? (int)((~sup[i >> 5] >> (i & 31)) & 1u) : 0;
            lsum += c[q];
        }
        sscan[tid] = lsum;
    }
    __syncthreads();
    for (int off = 1; off < 256; off <<= 1) {
        int v = 0;
        if (tid < 256 && tid >= off) v = sscan[tid - off];
        __syncthreads();
        if (tid < 256) sscan[tid] += v;
        __syncthreads();
    }
    const int excl  = (tid < 256) ? (sscan[tid] - lsum) : 0;
    const int total = sscan[255];

    float* ob  = out + n * POST_N * 4;
    float* osc = out + NIMG * POST_N * 4 + n * POST_N;
    float* ovd = out + NIMG * POST_N * 5 + n * POST_N;

    for (int i = tid; i < POST_N * 4; i += 512) ob[i] = 0.0f;
    for (int i = tid; i < POST_N; i += 512) osc[i] = 0.0f;
    const int lim = min(total, POST_N);
    for (int i = tid; i < POST_N; i += 512) ovd[i] = (i < lim) ? 1.0f : 0.0f;
    __syncthreads();

    if (tid < 256) {
        int run = excl;
        for (int q = 0; q < 8; ++q) {
            const int i = base8 + q;
            if (i < PRE_N && c[q]) {
                if (run < POST_N) {
                    float4 b = ((const float4*)wsBoxes)[n * PRE_N + i];
                    ob[run * 4 + 0] = b.x;
                    ob[run * 4 + 1] = b.y;
                    ob[run * 4 + 2] = b.z;
                    ob[run * 4 + 3] = b.w;
                    osc[run] = wsScores[n * PRE_N + i];
                }
                run++;
            }
        }
    }
}

extern "C" void kernel_launch(void* const* d_in, const int* in_sizes, int n_in,
                              void* d_out, int out_size, void* d_ws, size_t ws_size,
                              hipStream_t stream) {
    const float* obj  = (const float*)d_in[0];
    const float* breg = (const float*)d_in[1];
    // d_in[2] anchors unused (computed inline, exact in f32)
    float* ws        = (float*)d_ws;
    float* wsBoxes   = ws;                      // 64000 floats
    float* wsScores  = ws + 64000;              // 16000 floats
    int*   wsValid   = (int*)(ws + 80000);      // 16000 ints
    uint64_t* wsMask = (uint64_t*)(ws + 96000); // 8*2000*32 u64 = 4.096 MB

    topk_decode<<<NIMG, 1024, 0, stream>>>(obj, breg, wsBoxes, wsScores, wsValid);
    nms_mask<<<NIMG * 32, 512, 0, stream>>>(wsBoxes, wsMask);
    nms_scan_select<<<NIMG, 512, 0, stream>>>(wsBoxes, wsScores, wsValid, wsMask,
                                              (float*)d_out);
}

// Round 8
// 150.795 us; speedup vs baseline: 1.1239x; 1.1239x over previous
//
#include <hip/hip_runtime.h>
#include <math.h>
#include <stdint.h>

#define NIMG   8
#define NA     30000      // H*W*A = 100*100*3
#define NQ4    7500       // NA/4 float4s
#define PRE_N  2000
#define POST_N 1000
#define NMS_TH 0.7f
#define DCLIP  4.135166556742356f   // log(1000/16)
#define IMGF   1600.0f
#define IMGM1  1599.0f
#define CAND_MAX 4096
#define HPITCH 4104       // 4096 + 8: replica bank-spread padding
#define BIG_BIN 64        // bins larger than this use the 2nd-level sub-radix
#define PREF_BIN 3064u    // keyof(1.0f)>>20: pass-1 prefilter pivot (fallback-safe)

// ws layout (floats): boxes [8][2000][4] @0, scores [8][2000] @64000,
//   valid(int) [8][2000] @80000, mask(u64) [8][2000][32] @96000.

// ---------------------------------------------------------------------------
// decode + store helper (verified math, unchanged)
// ---------------------------------------------------------------------------
__device__ __forceinline__ void decode_store(
    uint64_t key, unsigned int rank, int n, const float* __restrict__ breg,
    float* __restrict__ wsBoxes, float* __restrict__ wsScores,
    int* __restrict__ wsValid)
{
    unsigned int idx = (unsigned int)key;
    unsigned int k   = ~((unsigned int)(key >> 32));
    unsigned int u   = (k & 0x80000000u) ? (k & 0x7fffffffu) : ~k;
    float logit = __uint_as_float(u);
    float score = 1.0f / (1.0f + expf(-logit));

    int a = idx % 3, t = idx / 3, w = t % 100, h = t / 100;
    const float* bp = breg + n*120000 + (a*4)*10000 + t;
    float dx = bp[0], dy = bp[10000], dw = bp[20000], dh = bp[30000];

    float half = (a == 0) ? 32.0f : ((a == 1) ? 64.0f : 128.0f);
    float cx = w * 16.0f + 8.0f, cy = h * 16.0f + 8.0f;
    float x1 = cx - half, y1 = cy - half, x2 = cx + half, y2 = cy + half;
    float wd = x2 - x1 + 1.0f, hg = y2 - y1 + 1.0f;
    float cxr = x1 + 0.5f * wd, cyr = y1 + 0.5f * hg;
    dw = fminf(dw, DCLIP); dh = fminf(dh, DCLIP);
    float pcx = dx * wd + cxr, pcy = dy * hg + cyr;
    float pw = expf(dw) * wd, ph = expf(dh) * hg;
    float px1 = pcx - 0.5f * pw, py1 = pcy - 0.5f * ph;
    float px2 = pcx + 0.5f * pw - 1.0f, py2 = pcy + 0.5f * ph - 1.0f;
    px1 = fminf(fmaxf(px1, 0.0f), IMGM1);
    px2 = fminf(fmaxf(px2, 0.0f), IMGM1);
    py1 = fminf(fmaxf(py1, 0.0f), IMGM1);
    py2 = fminf(fmaxf(py2, 0.0f), IMGM1);
    float wss = px2 - px1 + 1.0f, hss = py2 - py1 + 1.0f;
    float xc = px1 + wss * 0.5f, yc = py1 + hss * 0.5f;
    int valid = (wss >= 0.0f) && (hss >= 0.0f) && (xc < IMGF) && (yc < IMGF);

    ((float4*)wsBoxes)[n * PRE_N + (int)rank] = make_float4(px1, py1, px2, py2);
    wsScores[n * PRE_N + (int)rank] = score;
    wsValid [n * PRE_N + (int)rank] = valid;
}

__device__ __forceinline__ unsigned int keyof(float f) {
    unsigned int u = __float_as_uint(f);
    return (u & 0x80000000u) ? ~u : (u | 0x80000000u);
}

// ---------------------------------------------------------------------------
// Kernel AB (verified R6): fused hist + suffix-sum + bin-grouped rank + decode
// with pass-1 prefilter and combined 2nd-level sub-radix for big bins.
// ---------------------------------------------------------------------------
__global__ __launch_bounds__(1024) void topk_decode(
    const float* __restrict__ obj, const float* __restrict__ breg,
    float* __restrict__ wsBoxes, float* __restrict__ wsScores,
    int* __restrict__ wsValid)
{
    const int n    = blockIdx.x;
    const int tid  = threadIdx.x;
    const int lane = tid & 63;
    const int wid  = tid >> 6;
    const int rep  = wid & 3;

    __shared__ unsigned int   histf[4 * HPITCH]; // counts -> bump bases (~64KB)
    __shared__ unsigned short sufx[4096];        // bin start slots
    __shared__ uint64_t       grp[CAND_MAX];     // bin-grouped keys (32KB)
    __shared__ uint64_t       grp2[CAND_MAX];    // sub-grouped big-bin keys (32KB)
    __shared__ unsigned int   wsum[16];
    __shared__ unsigned int   sbstar;
    __shared__ unsigned int   lbbase[16];        // grp2 region base per big bin
    __shared__ unsigned int   lbcnt, lbtot;

    // overlays on dead histogram replicas (valid only AFTER pass 2):
    unsigned int*   hist2  = histf;                                  // [16*256] u32
    unsigned short* sufx2  = (unsigned short*)(histf + HPITCH);      // [4096] u16
    unsigned char*  bin2lb = (unsigned char*)(histf + 2 * HPITCH);   // [4096] u8

    for (int b = tid; b < 4 * HPITCH; b += 1024) histf[b] = 0u;
    __syncthreads();

    // ---- load this thread's 8 float4s once (8 outstanding loads) -----------
    const float4* obj4 = (const float4*)(obj + n * NA);   // 7500 float4
    float4 v[8];
    #pragma unroll
    for (int kk = 0; kk < 7; ++kk) v[kk] = obj4[tid + kk * 1024];
    v[7] = make_float4(0.f, 0.f, 0.f, 0.f);
    if (tid < NQ4 - 7 * 1024) v[7] = obj4[tid + 7 * 1024];   // 332 tail threads

    // ---- pass 1: prefiltered replica histogram from registers --------------
    #pragma unroll
    for (int kk = 0; kk < 8; ++kk) {
        if (kk == 7 && tid >= NQ4 - 7 * 1024) continue;
        const float fv[4] = {v[kk].x, v[kk].y, v[kk].z, v[kk].w};
        #pragma unroll
        for (int e = 0; e < 4; ++e) {
            unsigned int b = keyof(fv[e]) >> 20;
            if (b >= PREF_BIN)
                atomicAdd(&histf[rep * HPITCH + b], 1u);
        }
    }
    __syncthreads();

    // ---- totals + fallback check -------------------------------------------
    unsigned int c0, c1, c2, c3;
    {
        const int b0 = tid * 4;
        c0 = histf[b0+0] + histf[HPITCH+b0+0] + histf[2*HPITCH+b0+0] + histf[3*HPITCH+b0+0];
        c1 = histf[b0+1] + histf[HPITCH+b0+1] + histf[2*HPITCH+b0+1] + histf[3*HPITCH+b0+1];
        c2 = histf[b0+2] + histf[HPITCH+b0+2] + histf[2*HPITCH+b0+2] + histf[3*HPITCH+b0+2];
        c3 = histf[b0+3] + histf[HPITCH+b0+3] + histf[2*HPITCH+b0+3] + histf[3*HPITCH+b0+3];
    }
    unsigned int p = c0 + c1 + c2 + c3;
    unsigned int s = p;
    #pragma unroll
    for (int off = 1; off < 64; off <<= 1) {
        unsigned int vv = __shfl_down(s, off);
        if (lane + off < 64) s += vv;
    }
    if (lane == 0) wsum[wid] = s;
    __syncthreads();
    unsigned int ftotal = 0;
    for (int w = 0; w < 16; ++w) ftotal += wsum[w];

    if (ftotal < PRE_N) {
        // fallback (block-uniform): top-up with the skipped low bins, redo reduce
        #pragma unroll
        for (int kk = 0; kk < 8; ++kk) {
            if (kk == 7 && tid >= NQ4 - 7 * 1024) continue;
            const float fv[4] = {v[kk].x, v[kk].y, v[kk].z, v[kk].w};
            #pragma unroll
            for (int e = 0; e < 4; ++e) {
                unsigned int b = keyof(fv[e]) >> 20;
                if (b < PREF_BIN)
                    atomicAdd(&histf[rep * HPITCH + b], 1u);
            }
        }
        __syncthreads();
        {
            const int b0 = tid * 4;
            c0 = histf[b0+0] + histf[HPITCH+b0+0] + histf[2*HPITCH+b0+0] + histf[3*HPITCH+b0+0];
            c1 = histf[b0+1] + histf[HPITCH+b0+1] + histf[2*HPITCH+b0+1] + histf[3*HPITCH+b0+1];
            c2 = histf[b0+2] + histf[HPITCH+b0+2] + histf[2*HPITCH+b0+2] + histf[3*HPITCH+b0+2];
            c3 = histf[b0+3] + histf[HPITCH+b0+3] + histf[2*HPITCH+b0+3] + histf[3*HPITCH+b0+3];
        }
        p = c0 + c1 + c2 + c3;
        s = p;
        #pragma unroll
        for (int off = 1; off < 64; off <<= 1) {
            unsigned int vv = __shfl_down(s, off);
            if (lane + off < 64) s += vv;
        }
        __syncthreads();            // wsum reuse
        if (lane == 0) wsum[wid] = s;
        __syncthreads();
    }

    // ---- suffix-scan (verified structure), bump-base conversion ------------
    unsigned int wafter = 0;
    for (int w = wid + 1; w < 16; ++w) wafter += wsum[w];
    unsigned int after = (s - p) + wafter;   // elems in bins > 4t+3
    {
        unsigned int S3 = after + c3;        // elems in bins > 4t+2
        unsigned int S2 = S3 + c2;           // elems in bins > 4t+1
        unsigned int S1 = S2 + c1;           // elems in bins > 4t+0
        unsigned int S0 = S1 + c0;
        if (S3 >= PRE_N && after < PRE_N) { sbstar = tid*4+3; }
        if (S2 >= PRE_N && S3    < PRE_N) { sbstar = tid*4+2; }
        if (S1 >= PRE_N && S2    < PRE_N) { sbstar = tid*4+1; }
        if (S0 >= PRE_N && S1    < PRE_N) { sbstar = tid*4+0; }
        sufx[tid*4+0] = (unsigned short)S1;
        sufx[tid*4+1] = (unsigned short)S2;
        sufx[tid*4+2] = (unsigned short)S3;
        sufx[tid*4+3] = (unsigned short)after;

        // counts -> per-replica bump bases (each thread touches only own bins)
        const unsigned int st[4] = {S1, S2, S3, after};
        #pragma unroll
        for (int q = 0; q < 4; ++q) {
            const int b = tid*4 + q;
            unsigned int base = st[q];
            #pragma unroll
            for (int r = 0; r < 4; ++r) {
                unsigned int c = histf[r * HPITCH + b];
                histf[r * HPITCH + b] = base;
                base += c;
            }
        }
    }
    __syncthreads();
    const unsigned int bstar = sbstar;

    // ---- pass 2: bin-grouped placement from registers ----------------------
    #pragma unroll
    for (int kk = 0; kk < 8; ++kk) {
        if (kk == 7 && tid >= NQ4 - 7 * 1024) continue;
        const float fv[4] = {v[kk].x, v[kk].y, v[kk].z, v[kk].w};
        #pragma unroll
        for (int e = 0; e < 4; ++e) {
            unsigned int k = keyof(fv[e]);
            unsigned int b = k >> 20;
            if (b < bstar) continue;
            int j = (tid + kk * 1024) * 4 + e;
            int a = j / 10000, t = j - a * 10000;
            uint64_t key = (((uint64_t)(~k)) << 32) | (unsigned int)(t * 3 + a);
            unsigned int slot = atomicAdd(&histf[rep * HPITCH + b], 1u);
            if (slot < CAND_MAX) grp[slot] = key;
        }
    }
    __syncthreads();

    // after pass2, histf[3][b] = end of bin b's slot region (replica 3 stays live)
    const unsigned int total = min(histf[3 * HPITCH + bstar], (unsigned int)CAND_MAX);

    // ---- init overlays (replicas 0..2 now dead) ----------------------------
    ((unsigned int*)bin2lb)[tid] = 0xFFFFFFFFu;              // 4096 B
    hist2[tid] = 0u; hist2[tid+1024] = 0u; hist2[tid+2048] = 0u; hist2[tid+3072] = 0u;
    if (tid == 0) { lbcnt = 0u; lbtot = 0u; }
    __syncthreads();

    // ---- detect big bins (each thread owns bins 4t..4t+3) ------------------
    #pragma unroll
    for (int q = 0; q < 4; ++q) {
        const unsigned int b = (unsigned int)(tid*4 + q);
        if (b >= bstar) {
            const unsigned int ge  = min(histf[3*HPITCH + b], (unsigned int)CAND_MAX);
            const unsigned int cnt = ge - (unsigned int)sufx[b];
            if (cnt > (unsigned int)BIG_BIN) {
                unsigned int pos = atomicAdd(&lbcnt, 1u);
                if (pos < 16u) {
                    bin2lb[b] = (unsigned char)pos;
                    lbbase[pos] = atomicAdd(&lbtot, cnt);
                }
            }
        }
    }
    __syncthreads();

    // ---- count pass: sub-histogram on key bits 19:12 of hi(=~k) ------------
    for (unsigned int slot = tid; slot < total; slot += 1024) {
        const unsigned int hi = (unsigned int)(grp[slot] >> 32);
        const unsigned int b  = 4095u - (hi >> 20);
        const unsigned char lb = bin2lb[b];
        if (lb != 0xFFu)
            atomicAdd(&hist2[(unsigned int)lb * 256u + ((hi >> 12) & 0xFFu)], 1u);
    }
    __syncthreads();

    // ---- per-big-bin 256-entry exclusive prefix: wave w <-> big bin w ------
    {
        const unsigned int nlb = min(lbcnt, 16u);
        if ((unsigned int)wid < nlb) {
            const int xb = wid * 256 + lane * 4;
            unsigned int e0 = hist2[xb+0], e1 = hist2[xb+1],
                         e2 = hist2[xb+2], e3 = hist2[xb+3];
            unsigned int tsum = e0 + e1 + e2 + e3;
            unsigned int inc = tsum;
            #pragma unroll
            for (int off = 1; off < 64; off <<= 1) {
                unsigned int vv = __shfl_up(inc, off);
                if (lane >= off) inc += vv;
            }
            unsigned int base = lbbase[wid] + (inc - tsum);
            hist2[xb+0] = base;             sufx2[xb+0] = (unsigned short)base;
            base += e0; hist2[xb+1] = base; sufx2[xb+1] = (unsigned short)base;
            base += e1; hist2[xb+2] = base; sufx2[xb+2] = (unsigned short)base;
            base += e2; hist2[xb+3] = base; sufx2[xb+3] = (unsigned short)base;
        }
    }
    __syncthreads();

    // ---- regroup big-bin elems into grp2 (bump on hist2) -------------------
    for (unsigned int slot = tid; slot < total; slot += 1024) {
        const uint64_t key = grp[slot];
        const unsigned int hi = (unsigned int)(key >> 32);
        const unsigned int b  = 4095u - (hi >> 20);
        const unsigned char lb = bin2lb[b];
        if (lb != 0xFFu) {
            unsigned int d = atomicAdd(&hist2[(unsigned int)lb * 256u + ((hi >> 12) & 0xFFu)], 1u);
            grp2[d] = key;
        }
    }
    __syncthreads();

    // ---- final: rank + decode ----------------------------------------------
    for (unsigned int slot = tid; slot < total; slot += 1024) {
        const uint64_t key = grp[slot];
        const unsigned int hi = (unsigned int)(key >> 32);   // = ~k
        const unsigned int b  = 4095u - (hi >> 20);
        const unsigned int gbeg = sufx[b];
        const unsigned int gend = min(histf[3 * HPITCH + b], (unsigned int)CAND_MAX);
        const unsigned char lb  = bin2lb[b];
        unsigned int rank;

        if (lb != 0xFFu) {
            // big bin: sub-group scan (avg ~5 elems), predicated 8-wide
            const unsigned int x   = (unsigned int)lb * 256u + ((hi >> 12) & 0xFFu);
            const unsigned int s2  = sufx2[x];
            const unsigned int e2v = hist2[x];     // post-bump = sub-group end
            rank = gbeg + (s2 - lbbase[lb]);
            for (unsigned int g = s2; g < e2v; g += 8u) {
                #pragma unroll
                for (int i = 0; i < 8; ++i) {
                    const unsigned int gi = g + (unsigned int)i;
                    const uint64_t vv = grp2[min(gi, e2v - 1u)];
                    rank += (gi < e2v && vv < key) ? 1u : 0u;
                }
            }
        } else {
            // small bin: 8-wide unrolled scan over grp
            rank = gbeg;
            unsigned int g = gbeg;
            for (; g + 8u <= gend; g += 8u) {
                uint64_t v0 = grp[g+0], v1 = grp[g+1], v2 = grp[g+2], v3 = grp[g+3];
                uint64_t v4 = grp[g+4], v5 = grp[g+5], v6 = grp[g+6], v7 = grp[g+7];
                unsigned int r0 = (v0 < key) ? 1u : 0u;
                r0 += (v1 < key) ? 1u : 0u;
                r0 += (v2 < key) ? 1u : 0u;
                r0 += (v3 < key) ? 1u : 0u;
                r0 += (v4 < key) ? 1u : 0u;
                r0 += (v5 < key) ? 1u : 0u;
                r0 += (v6 < key) ? 1u : 0u;
                r0 += (v7 < key) ? 1u : 0u;
                rank += r0;
            }
            for (; g < gend; ++g)
                rank += (grp[g] < key) ? 1u : 0u;
        }
        if (rank >= PRE_N) continue;
        decode_store(key, rank, n, breg, wsBoxes, wsScores, wsValid);
    }
}

// ---------------------------------------------------------------------------
// Kernel C (verified R11, unchanged): div-free IoU predicate, ballot mask
// word, LDS-staged contiguous store. One block (8 waves) per row-tile.
// ---------------------------------------------------------------------------
__global__ __launch_bounds__(512) void nms_mask(
    const float* __restrict__ wsBoxes, uint64_t* __restrict__ mask)
{
    const int blk  = blockIdx.x;
    const int n    = blk >> 5;
    const int i_t  = blk & 31;
    const int tid  = threadIdx.x;
    const int lane = tid & 63;
    const int wv   = tid >> 6;   // 0..7

    __shared__ uint64_t tile[64 * 33];   // padded pitch 33

    for (int idx = tid; idx < 64 * 33; idx += 512) tile[idx] = 0ull;
    __syncthreads();

    const int r = i_t * 64 + lane;
    float4 rb = (r < PRE_N) ? ((const float4*)wsBoxes)[n * PRE_N + r]
                            : make_float4(0.f, 0.f, 0.f, 0.f);
    float ra = (rb.z - rb.x + 1.0f) * (rb.w - rb.y + 1.0f);

    for (int j_t = i_t + wv; j_t < 32; j_t += 8) {
        const int j = j_t * 64 + lane;
        float4 cb = (j < PRE_N) ? ((const float4*)wsBoxes)[n * PRE_N + j]
                                : make_float4(3e30f, 3e30f, 3e30f, 3e30f);
        float ca = (cb.z - cb.x + 1.0f) * (cb.w - cb.y + 1.0f);
        const uint64_t jmask = (j_t == 31) ? 0xFFFFull : ~0ull;
        const bool diag = (j_t == i_t);
        uint64_t myword = 0ull;

        #pragma unroll
        for (int c = 0; c < 64; ++c) {
            float rx1 = __int_as_float(__builtin_amdgcn_readlane(__float_as_int(rb.x), c));
            float ry1 = __int_as_float(__builtin_amdgcn_readlane(__float_as_int(rb.y), c));
            float rx2 = __int_as_float(__builtin_amdgcn_readlane(__float_as_int(rb.z), c));
            float ry2 = __int_as_float(__builtin_amdgcn_readlane(__float_as_int(rb.w), c));
            float rar = __int_as_float(__builtin_amdgcn_readlane(__float_as_int(ra), c));
            float xx1 = fmaxf(rx1, cb.x), yy1 = fmaxf(ry1, cb.y);
            float xx2 = fminf(rx2, cb.z), yy2 = fminf(ry2, cb.w);
            float ww = fmaxf(xx2 - xx1 + 1.0f, 0.0f);
            float hh = fmaxf(yy2 - yy1 + 1.0f, 0.0f);
            float inter = ww * hh;
            float denom = rar + ca - inter;
            unsigned long long bits = __ballot(inter > NMS_TH * denom) & jmask;
            if (diag) bits &= (c == 63) ? 0ull : ((~0ull) << (c + 1));
            if (lane == c) myword = bits;
        }
        tile[lane * 33 + j_t] = myword;
    }
    __syncthreads();

    uint64_t* mrow = mask + ((size_t)n * PRE_N + (size_t)i_t * 64) * 32;
    const int cmax = (i_t == 31) ? 16 : 64;
    for (int idx = tid; idx < cmax * 32; idx += 512) {
        const int rr = idx >> 5, w = idx & 31;
        mrow[idx] = tile[rr * 33 + w];
    }
}

// ---------------------------------------------------------------------------
// Kernel D (R8): group-serial greedy NMS. Same verified structure as R7
// (32 groups x 64 rows, wave0 serial scan + all-wave broadcast) with the two
// measured cost terms fixed:
//  (1) intra-group scan in inline asm: win lives in 2 SGPRs, 128 readlanes
//      hoisted off the chain; chain = 4 SALU/step (R7's HIP version compiled
//      to ~10 wave64 VALU 64-bit ops/step -> 40us of the 62).
//  (2) broadcast mask words register-prefetched one group ahead (R7 had the
//      global loads on the critical path between barriers).
// ---------------------------------------------------------------------------
#define NSA(b) \
    "v_readlane_b32 %[tlo], %[cl], " #b "\n\t" \
    "v_readlane_b32 %[thi], %[ch], " #b "\n\t" \
    "s_bitcmp1_b32 %[wlo], " #b "\n\t" \
    "s_cselect_b32 %[m], 0, -1\n\t" \
    "s_and_b32 %[tlo], %[tlo], %[m]\n\t" \
    "s_and_b32 %[thi], %[thi], %[m]\n\t" \
    "s_or_b32 %[wlo], %[wlo], %[tlo]\n\t" \
    "s_or_b32 %[whi], %[whi], %[thi]\n\t"

#define NSB(b, c) \
    "v_readlane_b32 %[tlo], %[cl], " #b "\n\t" \
    "v_readlane_b32 %[thi], %[ch], " #b "\n\t" \
    "s_bitcmp1_b32 %[whi], " #c "\n\t" \
    "s_cselect_b32 %[m], 0, -1\n\t" \
    "s_and_b32 %[tlo], %[tlo], %[m]\n\t" \
    "s_and_b32 %[thi], %[thi], %[m]\n\t" \
    "s_or_b32 %[wlo], %[wlo], %[tlo]\n\t" \
    "s_or_b32 %[whi], %[whi], %[thi]\n\t"

__global__ __launch_bounds__(512) void nms_scan_select(
    const float* __restrict__ wsBoxes, const float* __restrict__ wsScores,
    const int* __restrict__ wsValid, const uint64_t* __restrict__ mask,
    float* __restrict__ out)
{
    const int n    = blockIdx.x;
    const int tid  = threadIdx.x;
    const int lane = tid & 63;
    const int wid  = tid >> 6;

    __shared__ unsigned int sup[64];   // 2048-bit suppression (1 = dead/invalid)
    __shared__ unsigned int kml, kmh;  // current group's kept mask
    __shared__ int skept, sdone;
    __shared__ int sscan[256];

    if (tid < 64) sup[tid] = 0u;
    if (tid == 0) { skept = 0; sdone = 0; }
    __syncthreads();

    // invalid bits -> sup (rows 2000..2047 forced invalid)
    if (tid < 500) {
        int4 vv = ((const int4*)(wsValid + n * PRE_N))[tid];
        unsigned int nib = (vv.x ? 0u : 1u) | ((vv.y ? 0u : 1u) << 1)
                         | ((vv.z ? 0u : 1u) << 2) | ((vv.w ? 0u : 1u) << 3);
        if (nib) atomicOr(&sup[tid >> 3], nib << ((tid & 7) * 4));
    } else {
        atomicOr(&sup[tid >> 3], 0xFu << ((tid & 7) * 4));
    }
    __syncthreads();

    const uint64_t* mrow = mask + (size_t)n * PRE_N * 32;

    // broadcast assignment: thread = (row-quad r0, word w); double-buffered
    // register prefetch, loaded one group ahead.
    const int r0 = (tid >> 5) * 4;     // 0..60
    const int w  = tid & 31;           // u64 word index
    uint64_t pfc[4], pfn[4];
    #pragma unroll
    for (int q = 0; q < 4; ++q) {      // prefetch group 0
        const int r = r0 + q;
        pfn[q] = (w > 0 && r < PRE_N) ? mrow[(size_t)r * 32 + w] : 0ull;
    }

    // wave 0: preload group 0's intra column word (lane = row-in-group)
    unsigned int cl = 0u, ch = 0u;
    if (wid == 0) {
        uint64_t cw = (lane < PRE_N) ? mrow[(size_t)lane * 32 + 0] : 0ull;
        cl = (unsigned int)cw; ch = (unsigned int)(cw >> 32);
    }

    for (int g = 0; g < 32; ++g) {
        __syncthreads();            // sup from broadcast(g-1) ready; sdone visible
        if (sdone) break;

        // rotate prefetch buffer; issue loads for group g+1 (latency hides
        // under this group's scan + broadcast)
        #pragma unroll
        for (int q = 0; q < 4; ++q) pfc[q] = pfn[q];
        if (g < 31) {
            #pragma unroll
            for (int q = 0; q < 4; ++q) {
                const int r = (g + 1) * 64 + r0 + q;
                pfn[q] = (w > g + 1 && r < PRE_N) ? mrow[(size_t)r * 32 + w] : 0ull;
            }
        }

        if (wid == 0) {
            // prefetch next group's column word
            unsigned int nl = 0u, nh = 0u;
            if (g < 31) {
                const int r = (g + 1) * 64 + lane;
                uint64_t cw = (r < PRE_N) ? mrow[(size_t)r * 32 + (g + 1)] : 0ull;
                nl = (unsigned int)cw; nh = (unsigned int)(cw >> 32);
            }

            unsigned int wlo = (unsigned int)__builtin_amdgcn_readfirstlane((int)sup[2*g]);
            unsigned int whi = (unsigned int)__builtin_amdgcn_readfirstlane((int)sup[2*g+1]);
            int tlo_, thi_, m_;
            asm volatile(
                NSA(0)  NSA(1)  NSA(2)  NSA(3)  NSA(4)  NSA(5)  NSA(6)  NSA(7)
                NSA(8)  NSA(9)  NSA(10) NSA(11) NSA(12) NSA(13) NSA(14) NSA(15)
                NSA(16) NSA(17) NSA(18) NSA(19) NSA(20) NSA(21) NSA(22) NSA(23)
                NSA(24) NSA(25) NSA(26) NSA(27) NSA(28) NSA(29) NSA(30) NSA(31)
                NSB(32,0)  NSB(33,1)  NSB(34,2)  NSB(35,3)
                NSB(36,4)  NSB(37,5)  NSB(38,6)  NSB(39,7)
                NSB(40,8)  NSB(41,9)  NSB(42,10) NSB(43,11)
                NSB(44,12) NSB(45,13) NSB(46,14) NSB(47,15)
                NSB(48,16) NSB(49,17) NSB(50,18) NSB(51,19)
                NSB(52,20) NSB(53,21) NSB(54,22) NSB(55,23)
                NSB(56,24) NSB(57,25) NSB(58,26) NSB(59,27)
                NSB(60,28) NSB(61,29) NSB(62,30) NSB(63,31)
                : [wlo]"+s"(wlo), [whi]"+s"(whi),
                  [tlo]"=&s"(tlo_), [thi]"=&s"(thi_), [m]"=&s"(m_)
                : [cl]"v"(cl), [ch]"v"(ch)
                : "scc");

            if (lane == 0) {
                sup[2*g]     = wlo;
                sup[2*g + 1] = whi;
                unsigned int kl = ~wlo, kh = ~whi;
                kml = kl; kmh = kh;
                int nk = skept + __popc(kl) + __popc(kh);
                skept = nk;
                if (nk >= POST_N) sdone = 1;
            }
            cl = nl; ch = nh;
        }
        __syncthreads();            // km + sup writeback visible

        if (!sdone && w > g) {
            // broadcast: OR kept rows' prefetched mask words into sup
            const unsigned long long km =
                ((unsigned long long)kmh << 32) | kml;
            unsigned long long acc = 0ull;
            #pragma unroll
            for (int q = 0; q < 4; ++q) {
                if ((km >> (r0 + q)) & 1ull) acc |= pfc[q];
            }
            if (acc) {
                atomicOr(&sup[2*w],     (unsigned int)acc);
                atomicOr(&sup[2*w + 1], (unsigned int)(acc >> 32));
            }
        }
    }
    __syncthreads();

    // ---- compaction + output (keep = ~sup) ---------------------------------
    int c[8];
    int lsum = 0;
    const int base8 = tid * 8;
    if (tid < 256) {
        for (int q = 0; q < 8; ++q) {
            const int i = base8 + q;
            c[q] = (i < PRE_N) ? (int)((~sup[i >> 5] >> (i & 31)) & 1u) : 0;
            lsum += c[q];
        }
        sscan[tid] = lsum;
    }
    __syncthreads();
    for (int off = 1; off < 256; off <<= 1) {
        int v = 0;
        if (tid < 256 && tid >= off) v = sscan[tid - off];
        __syncthreads();
        if (tid < 256) sscan[tid] += v;
        __syncthreads();
    }
    const int excl  = (tid < 256) ? (sscan[tid] - lsum) : 0;
    const int total = sscan[255];

    float* ob  = out + n * POST_N * 4;
    float* osc = out + NIMG * POST_N * 4 + n * POST_N;
    float* ovd = out + NIMG * POST_N * 5 + n * POST_N;

    for (int i = tid; i < POST_N * 4; i += 512) ob[i] = 0.0f;
    for (int i = tid; i < POST_N; i += 512) osc[i] = 0.0f;
    const int lim = min(total, POST_N);
    for (int i = tid; i < POST_N; i += 512) ovd[i] = (i < lim) ? 1.0f : 0.0f;
    __syncthreads();

    if (tid < 256) {
        int run = excl;
        for (int q = 0; q < 8; ++q) {
            const int i = base8 + q;
            if (i < PRE_N && c[q]) {
                if (run < POST_N) {
                    float4 b = ((const float4*)wsBoxes)[n * PRE_N + i];
                    ob[run * 4 + 0] = b.x;
                    ob[run * 4 + 1] = b.y;
                    ob[run * 4 + 2] = b.z;
                    ob[run * 4 + 3] = b.w;
                    osc[run] = wsScores[n * PRE_N + i];
                }
                run++;
            }
        }
    }
}

extern "C" void kernel_launch(void* const* d_in, const int* in_sizes, int n_in,
                              void* d_out, int out_size, void* d_ws, size_t ws_size,
                              hipStream_t stream) {
    const float* obj  = (const float*)d_in[0];
    const float* breg = (const float*)d_in[1];
    // d_in[2] anchors unused (computed inline, exact in f32)
    float* ws        = (float*)d_ws;
    float* wsBoxes   = ws;                      // 64000 floats
    float* wsScores  = ws + 64000;              // 16000 floats
    int*   wsValid   = (int*)(ws + 80000);      // 16000 ints
    uint64_t* wsMask = (uint64_t*)(ws + 96000); // 8*2000*32 u64 = 4.096 MB

    topk_decode<<<NIMG, 1024, 0, stream>>>(obj, breg, wsBoxes, wsScores, wsValid);
    nms_mask<<<NIMG * 32, 512, 0, stream>>>(wsBoxes, wsMask);
    nms_scan_select<<<NIMG, 512, 0, stream>>>(wsBoxes, wsScores, wsValid, wsMask,
                                              (float*)d_out);
}